// Round 6
// baseline (145.314 us; speedup 1.0000x reference)
//
#include <hip/hip_runtime.h>
#include <hip/hip_bf16.h>

typedef __bf16 bf16;
typedef bf16 bf16x4 __attribute__((ext_vector_type(4)));
typedef bf16 bf16x8 __attribute__((ext_vector_type(8)));
typedef short s16x4 __attribute__((ext_vector_type(4)));
typedef float f32x4 __attribute__((ext_vector_type(4)));

#define MFMA32(A, B, C) __builtin_amdgcn_mfma_f32_16x16x32_bf16(A, B, C, 0, 0, 0)
#define MFMA16(A, B, C) __builtin_amdgcn_mfma_f32_16x16x16bf16_1k(A, B, C, 0, 0, 0)
#define GL2LDS16(gp, lp)                                                            \
  __builtin_amdgcn_global_load_lds((const __attribute__((address_space(1))) unsigned int*)(gp), \
                                   (__attribute__((address_space(3))) unsigned int*)(lp), 16, 0, 0)

static constexpr float SCALE = 0.17677669529663687f;  // 1/sqrt(32)
static constexpr float LOG2E = 1.4426950408889634f;

// ---------------- prep (shrunk): convert x, transpose+convert weights.
// Bias-tile gather moved into k_gemm<0>'s launch (independent of xb/wtq; overlaps
// with gemm0 compute instead of serializing before it).
__global__ __launch_bounds__(256) void k_prep(const float* __restrict__ x,
                                              const float* __restrict__ wqkv,
                                              const float* __restrict__ wout,
                                              bf16* __restrict__ xb, bf16* __restrict__ wtq,
                                              bf16* __restrict__ wto) {
  const int tid = threadIdx.x;
  const int blk = blockIdx.x;
  if (blk < 2048) {
    int t = blk * 256 + tid;
    const float4* s = reinterpret_cast<const float4*>(x) + (size_t)t * 2;
    float4 a = s[0], c = s[1];
    bf16x8 o;
    o[0] = (bf16)a.x; o[1] = (bf16)a.y; o[2] = (bf16)a.z; o[3] = (bf16)a.w;
    o[4] = (bf16)c.x; o[5] = (bf16)c.y; o[6] = (bf16)c.z; o[7] = (bf16)c.w;
    reinterpret_cast<bf16x8*>(xb)[t] = o;
  } else {
    int t = (blk - 2048) * 256 + tid;
    if (t < 196608) {
      int n = t >> 8, k = t & 255;
      wtq[t] = (bf16)wqkv[k * 768 + n];
    } else {
      int t2 = t - 196608;
      int n = t2 >> 8, k = t2 & 255;
      wto[t2] = (bf16)wout[k * 256 + n];
    }
  }
}

// ------------------------ 128x128x(BK=32) bf16 MFMA GEMM, m97-style GL2LDS staging
// EPI 0: grid y in [0,6) = GEMM blocks; y in [6,38) = bias-gather blocks (moved from
//   prep): rbb[h][qt64][kt64][lane64][r4] = bias[qrow][key]*LOG2E. These are
//   memory-bound and backfill CUs as the 768 GEMM blocks retire.
//   GEMM epilogue: q (*scale*log2e) [b,h,n,d]; k [b,h,n,d]; v -> vt[b,h,d,n] via
//   LDS transpose (132-padded tile, coalesced bf16x8 stores).
// EPI 1: out epilogue -> fp32 out[m][256] + b_out
// NOTE: all GL2LDS prefetches are guarded (kt < 224) so none is outstanding at
// kernel exit — dangling LDS-DMA corrupts the successor block's LDS (r9 bug).
template <int EPI>
__global__ __launch_bounds__(256) void k_gemm(const bf16* __restrict__ A,
                                              const bf16* __restrict__ Bt,
                                              bf16* __restrict__ q, bf16* __restrict__ kk,
                                              bf16* __restrict__ vt, float* __restrict__ out,
                                              const float* __restrict__ bout,
                                              const float* __restrict__ table,
                                              const int* __restrict__ ridx,
                                              bf16* __restrict__ rbb) {
  // 33 KB shared: staging As[2][4096] | Bs[2][4096], reused post-loop as the
  // 128x132-padded transpose tile T (16896 elems) for the vt epilogue.
  __shared__ __align__(16) bf16 SM[16896];
  const int tid = threadIdx.x;
  if (EPI == 0 && blockIdx.y >= 6) {
    // ---------------- bias-gather blocks (no LDS, no barriers) ----------------
    const int bb2 = (blockIdx.y - 6) * 128 + blockIdx.x;  // (qt,kt) tile in [0,4096)
    const int qt = bb2 >> 6, kt = bb2 & 63;
    const int r = tid & 3, lane = tid >> 2;
    const int ln = lane & 15, quad = lane >> 4;
    const int qrow = qt * 16 + ln;
    const int key = kt * 16 + quad * 4 + r;
    const int idx = ridx[qrow * 1024 + key];
    const float4* p = reinterpret_cast<const float4*>(table) + idx * 2;
    float4 a = p[0], c = p[1];
    float vals[8] = {a.x, a.y, a.z, a.w, c.x, c.y, c.z, c.w};
    const int base = bb2 * 256 + tid;
#pragma unroll
    for (int h = 0; h < 8; ++h) rbb[h * 1048576 + base] = (bf16)(vals[h] * LOG2E);
    return;
  }
  bf16(*As)[4096] = reinterpret_cast<bf16(*)[4096]>(SM);
  bf16(*Bs)[4096] = reinterpret_cast<bf16(*)[4096]>(SM + 8192);
  const int ln = tid & 15, quad = (tid >> 4) & 3, wv = tid >> 6;
  const int wm = (wv >> 1) * 64, wn = (wv & 1) * 64;
  const int m0 = blockIdx.x * 128, n0 = blockIdx.y * 128;
  const int srow = tid >> 2, scg = (tid & 3) * 8;
  const bf16* ag = A + (size_t)(m0 + srow) * 256 + scg;
  const bf16* bg = Bt + (size_t)(n0 + srow) * 256 + scg;
  f32x4 acc[4][4] = {};

  GL2LDS16(ag, &As[0][tid * 8]);
  GL2LDS16(ag + 64 * 256, &As[0][2048 + tid * 8]);
  GL2LDS16(bg, &Bs[0][tid * 8]);
  GL2LDS16(bg + 64 * 256, &Bs[0][2048 + tid * 8]);

#pragma unroll 2
  for (int kt = 0; kt < 256; kt += 32) {
    const int cur = (kt >> 5) & 1, nxt = cur ^ 1;
    __syncthreads();
    if (kt < 224) {
      GL2LDS16(ag + kt + 32, &As[nxt][tid * 8]);
      GL2LDS16(ag + 64 * 256 + kt + 32, &As[nxt][2048 + tid * 8]);
      GL2LDS16(bg + kt + 32, &Bs[nxt][tid * 8]);
      GL2LDS16(bg + 64 * 256 + kt + 32, &Bs[nxt][2048 + tid * 8]);
    }
    bf16x8 af[4], bfr[4];
#pragma unroll
    for (int i = 0; i < 4; ++i)
      af[i] = *reinterpret_cast<const bf16x8*>(&As[cur][(wm + i * 16 + ln) * 32 + quad * 8]);
#pragma unroll
    for (int i = 0; i < 4; ++i)
      bfr[i] = *reinterpret_cast<const bf16x8*>(&Bs[cur][(wn + i * 16 + ln) * 32 + quad * 8]);
#pragma unroll
    for (int i = 0; i < 4; ++i)
#pragma unroll
      for (int j = 0; j < 4; ++j) acc[i][j] = MFMA32(af[i], bfr[j], acc[i][j]);
  }

  if (EPI == 0) {
    const int colbase = n0 + wn;
    const int seg = colbase >> 8;  // block-uniform: y∈{0,1}->q, {2,3}->k, {4,5}->v
    if (seg == 2) {
      // ---- vt epilogue via LDS transpose (coalesced stores) ----
      __syncthreads();  // all waves done with As/Bs reads (no DMA outstanding: kt<224 guard)
#pragma unroll
      for (int i = 0; i < 4; ++i) {
#pragma unroll
        for (int j = 0; j < 4; ++j) {
          bf16x4 t;
#pragma unroll
          for (int r = 0; r < 4; ++r) t[r] = (bf16)acc[i][j][r];
          // T[col][row], padded stride 132: write 4 rows (r) contiguously
          *reinterpret_cast<bf16x4*>(&SM[(wn + j * 16 + ln) * 132 + wm + i * 16 + quad * 4]) = t;
        }
      }
      __syncthreads();
      const int b = m0 >> 10;
      const int nbase = m0 & 1023;  // 128-row tile never crosses a batch boundary
      const int rc = tid & 15, c0 = tid >> 4;
      const int cb0 = n0 & 255;
#pragma unroll
      for (int p = 0; p < 8; ++p) {
        const int c = c0 + p * 16;
        const int gcol = cb0 + c;
        const int h = gcol >> 5, d = gcol & 31;
        bf16* dst = &vt[(b * 8 + h) * 32768 + d * 1024 + nbase + rc * 8];
        *reinterpret_cast<bf16x8*>(dst) =
            *reinterpret_cast<const bf16x8*>(&SM[c * 132 + rc * 8]);
      }
    } else {
      const int cb = colbase & 255;
      const float mul = (seg == 0) ? SCALE * LOG2E : 1.0f;
#pragma unroll
      for (int i = 0; i < 4; ++i) {
        const int gm = m0 + wm + i * 16 + quad * 4;
        const int b = gm >> 10;
#pragma unroll
        for (int j = 0; j < 4; ++j) {
          const int gc = cb + j * 16 + ln;
          const int h = gc >> 5, d = gc & 31;
#pragma unroll
          for (int r = 0; r < 4; ++r) {
            const int nseq = (gm + r) & 1023;
            bf16* dst = (seg == 0) ? q : kk;
            dst[(b * 8 + h) * 32768 + nseq * 32 + d] = (bf16)(acc[i][j][r] * mul);
          }
        }
      }
    }
  } else {
#pragma unroll
    for (int j = 0; j < 4; ++j) {
      const int gc = n0 + wn + j * 16 + ln;
      const float bb = bout[gc];
#pragma unroll
      for (int i = 0; i < 4; ++i) {
        const int gm = m0 + wm + i * 16 + quad * 4;
#pragma unroll
        for (int r = 0; r < 4; ++r) out[(size_t)(gm + r) * 256 + gc] = acc[i][j][r] + bb;
      }
    }
  }
}

// ----------------------------------------------------------------- flash attention
// v7 = R4's v3-KVBLK64 skeleton (best measured: KVBLK=128 was neutral-negative,
// ring-3 counted-vmcnt was negative — both reverted) + ones-MFMA row-sum:
//   lsum was 32 dependent VALU adds/iter (16-deep serial chain through lsum0)
//   + 12 end-of-kernel shuffles. Replaced by 8 MFMA16(p, ones, ls)/iter on the
//   24%-busy MFMA pipe: with B = all-ones, D[q][c] = sum_k P[q,k] lands in the
//   SAME C rows as PV output (reg r = row quad*4+r), so inv = rcp(ls[r]) directly.
//   Denominator now sums bf16-rounded P (same values as the PV numerator — errors
//   correlate; relative drift ~1e-4 over 1024 keys).
// Keeps both-sides XOR swizzles (Ks block-XOR, Vs [d32][key64] col-XOR) and the
// q-pair (32 rows/wave, grid 1024 = 4 blocks/CU).
// All GL2LDS prefetches guarded (it < 15) + trailing barrier: no dangling LDS-DMA.
__global__ __launch_bounds__(256, 4) void k_flash(const bf16* __restrict__ qs,
                                                  const bf16* __restrict__ ks,
                                                  const bf16* __restrict__ vtg,
                                                  const bf16* __restrict__ rbb,
                                                  bf16* __restrict__ ao) {
  __shared__ __align__(16) bf16 Ks[2][2048];  // [buf][row64][d32], block-swizzled
  __shared__ __align__(16) bf16 Vs[2][2048];  // [buf][d32][key64], col-swizzled
  const int tid = threadIdx.x;
  const int lane = tid & 63;
  const int ln = lane & 15, quad = lane >> 4, wv = tid >> 6;
  const int blk = blockIdx.x;
  const int bh = blk & 127;  // %8 == h -> XCD affinity
  const int b = bh >> 3, h = bh & 7;
  const int qtw = (blk >> 7) * 4 + wv;  // 32-row q-pair index [0,32)
  const int q0 = qtw * 32;
  const bf16* qb = qs + bh * 32768;
  const bf16* kb = ks + bh * 32768;
  const bf16* vb = vtg + bh * 32768;
  // bias pointers for the two 16-row q-tiles (qt = 2*qtw, 2*qtw+1)
  const bf16* bbias0 = rbb + h * 1048576 + (2 * qtw) * 16384 + lane * 4;  // + kt16*256
  const bf16* bbias1 = bbias0 + 16384;

  // K staging source: lane covers LDS (r = tid>>2, block b = tid&3); content is
  // global block b ^ ((r>>1)&3). Same 64B/row coverage -> coalescing unchanged.
  const bf16* kg = kb + (tid >> 2) * 32 + (((tid & 3) ^ ((tid >> 3) & 3)) * 8);  // + k0*32
  // V staging source: lane covers LDS (d = tid>>3, col c = tid&7); content is global
  // column c ^ (d&7) of vt row d (contiguous 128B per 8-lane group, permuted within).
  const bf16* vg = vb + (tid >> 3) * 1024 + (((tid & 7) ^ ((tid >> 3) & 7)) * 8);  // + k0

  // Q as B-operand of MFMA32: B[k=d=quad*8+j][n=qrow=ln]
  const bf16x8 qfrag0 = *reinterpret_cast<const bf16x8*>(&qb[(q0 + ln) * 32 + quad * 8]);
  const bf16x8 qfrag1 = *reinterpret_cast<const bf16x8*>(&qb[(q0 + 16 + ln) * 32 + quad * 8]);

  // read-side swizzle indices (loop-invariant)
  const int ksw = (quad ^ ((ln >> 1) & 3)) * 8;  // K 16B-block swizzle
  const int vswl = ln & 7;                       // V column swizzle XOR operand

  // all-ones bf16 B-frag for the row-sum MFMA (1.0bf16 = 0x3F80)
  const s16x4 onesb = {(short)0x3F80, (short)0x3F80, (short)0x3F80, (short)0x3F80};

  f32x4 a00 = {0.f, 0.f, 0.f, 0.f}, a01 = {0.f, 0.f, 0.f, 0.f};
  f32x4 a10 = {0.f, 0.f, 0.f, 0.f}, a11 = {0.f, 0.f, 0.f, 0.f};
  f32x4 ls0 = {0.f, 0.f, 0.f, 0.f}, ls1 = {0.f, 0.f, 0.f, 0.f};

  bf16x4 cbf[2][2][4];  // [buf][qtile][nt]
#pragma unroll
  for (int nt = 0; nt < 4; ++nt) {
    cbf[0][0][nt] = *reinterpret_cast<const bf16x4*>(&bbias0[nt * 256]);
    cbf[0][1][nt] = *reinterpret_cast<const bf16x4*>(&bbias1[nt * 256]);
  }
  GL2LDS16(kg, &Ks[0][tid * 8]);
  GL2LDS16(vg, &Vs[0][tid * 8]);

#pragma unroll 2
  for (int it = 0; it < 16; ++it) {
    const int cur = it & 1, nxt = cur ^ 1;
    const int k0 = it * 64;
    __syncthreads();  // tile `it` staged; prior iteration's LDS reads consumed
    if (it < 15) {    // guarded: NO dangling LDS-DMA at kernel exit
      GL2LDS16(kg + (k0 + 64) * 32, &Ks[nxt][tid * 8]);
      GL2LDS16(vg + k0 + 64, &Vs[nxt][tid * 8]);
#pragma unroll
      for (int nt = 0; nt < 4; ++nt) {
        cbf[nxt][0][nt] = *reinterpret_cast<const bf16x4*>(&bbias0[((it + 1) * 4 + nt) * 256]);
        cbf[nxt][1][nt] = *reinterpret_cast<const bf16x4*>(&bbias1[((it + 1) * 4 + nt) * 256]);
      }
    }
    // K frags: global K[k0+nt*16+ln][quad*8..+7] at swizzled block position
    bf16x8 kf[4];
#pragma unroll
    for (int nt = 0; nt < 4; ++nt)
      kf[nt] = *reinterpret_cast<const bf16x8*>(&Ks[cur][(nt * 16 + ln) * 32 + ksw]);
    // V B-frags for MFMA16: B[k=key=(2nt+q1)*8+q0*4+j][n=d]; Vs[d][key] col-swizzled
    s16x4 vfa[4], vfc[4];
#pragma unroll
    for (int nt = 0; nt < 4; ++nt) {
      const int col = ((2 * nt + (quad >> 1)) ^ vswl) * 8 + (quad & 1) * 4;
      vfa[nt] = *reinterpret_cast<const s16x4*>(&Vs[cur][ln * 64 + col]);
      vfc[nt] = *reinterpret_cast<const s16x4*>(&Vs[cur][(ln + 16) * 64 + col]);
    }
    // S^T = K*Q^T with bias C-init (exp2 domain; scale*log2e folded into q)
    f32x4 s0[4], s1[4];
#pragma unroll
    for (int nt = 0; nt < 4; ++nt) {
      f32x4 c0, c1;
#pragma unroll
      for (int e = 0; e < 4; ++e) {
        c0[e] = (float)cbf[cur][0][nt][e];
        c1[e] = (float)cbf[cur][1][nt][e];
      }
      s0[nt] = MFMA32(kf[nt], qfrag0, c0);
      s1[nt] = MFMA32(kf[nt], qfrag1, c1);
    }
    // P = exp2(S); pack to MFMA16 A-frags (register identity, r==j).
    // Row sums now via ones-MFMA (no VALU adds, no end shuffles).
    s16x4 p0[4], p1[4];
#pragma unroll
    for (int nt = 0; nt < 4; ++nt) {
      bf16x4 t0, t1;
#pragma unroll
      for (int e = 0; e < 4; ++e) {
        t0[e] = (bf16)__builtin_amdgcn_exp2f(s0[nt][e]);
        t1[e] = (bf16)__builtin_amdgcn_exp2f(s1[nt][e]);
      }
      p0[nt] = __builtin_bit_cast(s16x4, t0);
      p1[nt] = __builtin_bit_cast(s16x4, t1);
    }
#pragma unroll
    for (int nt = 0; nt < 4; ++nt) {
      a00 = MFMA16(p0[nt], vfa[nt], a00);
      a01 = MFMA16(p0[nt], vfc[nt], a01);
      ls0 = MFMA16(p0[nt], onesb, ls0);
      a10 = MFMA16(p1[nt], vfa[nt], a10);
      a11 = MFMA16(p1[nt], vfc[nt], a11);
      ls1 = MFMA16(p1[nt], onesb, ls1);
    }
  }
  __syncthreads();  // insurance: drain all waves' outstanding DMA before any exit

  // O C-layout: lane holds O[row=quad*4+r][d=ln (a*0) / 16+ln (a*1)]; ls*[r] holds
  // the matching row sum (every ln column identical).
#pragma unroll
  for (int r = 0; r < 4; ++r) {
    const float inv0 = __builtin_amdgcn_rcpf(ls0[r]);
    const int row0 = q0 + quad * 4 + r;
    bf16* po0 = &ao[(size_t)(b * 1024 + row0) * 256 + h * 32 + ln];
    po0[0] = (bf16)(a00[r] * inv0);
    po0[16] = (bf16)(a01[r] * inv0);
    const float inv1 = __builtin_amdgcn_rcpf(ls1[r]);
    const int row1 = q0 + 16 + quad * 4 + r;
    bf16* po1 = &ao[(size_t)(b * 1024 + row1) * 256 + h * 32 + ln];
    po1[0] = (bf16)(a10[r] * inv1);
    po1[16] = (bf16)(a11[r] * inv1);
  }
}

// ---------------------------------------------------------------------- launcher
extern "C" void kernel_launch(void* const* d_in, const int* in_sizes, int n_in,
                              void* d_out, int out_size, void* d_ws, size_t ws_size,
                              hipStream_t stream) {
  const float* x = (const float*)d_in[0];
  const float* wqkv = (const float*)d_in[1];
  const float* wout = (const float*)d_in[2];
  const float* bout = (const float*)d_in[3];
  const float* btab = (const float*)d_in[4];
  const int* ridx = (const int*)d_in[5];
  float* out = (float*)d_out;

  char* ws = (char*)d_ws;
  bf16* xb  = (bf16*)(ws + 0);           // 8 MB   [16384][256]
  bf16* wtq = (bf16*)(ws + 8388608);     // 384 KB
  bf16* wto = (bf16*)(ws + 8781824);     // 128 KB
  bf16* q   = (bf16*)(ws + 8912896);     // 8 MB   [b,h,n,d] (pre-scaled scale*log2e)
  bf16* k   = (bf16*)(ws + 17301504);    // 8 MB   [b,h,n,d]
  bf16* vt  = (bf16*)(ws + 25690112);    // 8 MB   [b,h,d,n]
  bf16* rb  = (bf16*)(ws + 34078720);    // 16 MB  S^T C-layout bias tiles (*log2e)
  bf16* ao  = (bf16*)(ws + 50855936);    // 8 MB   [16384][256]

  k_prep<<<3072, 256, 0, stream>>>(x, wqkv, wout, xb, wtq, wto);
  // y<6: GEMM (q/k/vt); y>=6: 4096 bias-gather blocks (overlap with GEMM compute)
  k_gemm<0><<<dim3(128, 38), 256, 0, stream>>>(xb, wtq, q, k, vt, nullptr, nullptr,
                                               btab, ridx, rb);
  k_flash<<<1024, 256, 0, stream>>>(q, k, vt, rb, ao);
  k_gemm<1><<<dim3(128, 2), 256, 0, stream>>>(ao, wto, nullptr, nullptr, nullptr, out, bout,
                                              nullptr, nullptr, nullptr);
}

// Round 7
// 139.231 us; speedup vs baseline: 1.0437x; 1.0437x over previous
//
#include <hip/hip_runtime.h>
#include <hip/hip_bf16.h>

typedef __bf16 bf16;
typedef bf16 bf16x4 __attribute__((ext_vector_type(4)));
typedef bf16 bf16x8 __attribute__((ext_vector_type(8)));
typedef short s16x4 __attribute__((ext_vector_type(4)));
typedef float f32x4 __attribute__((ext_vector_type(4)));

#define MFMA32(A, B, C) __builtin_amdgcn_mfma_f32_16x16x32_bf16(A, B, C, 0, 0, 0)
#define MFMA16(A, B, C) __builtin_amdgcn_mfma_f32_16x16x16bf16_1k(A, B, C, 0, 0, 0)
#define GL2LDS16(gp, lp)                                                            \
  __builtin_amdgcn_global_load_lds((const __attribute__((address_space(1))) unsigned int*)(gp), \
                                   (__attribute__((address_space(3))) unsigned int*)(lp), 16, 0, 0)

static constexpr float SCALE = 0.17677669529663687f;  // 1/sqrt(32)
static constexpr float LOG2E = 1.4426950408889634f;

// ---------------- merged prep (R4 state): convert x, transpose+convert weights,
// gather bias. Bias gather lives HERE (LDS-free kernel -> full occupancy; fusing it
// into gemm0 regressed: the 33KB static LDS capped the gather at 4 blocks/CU).
// bias layout (S^T C-layout): rbb[h][qt64][kt64][lane64][r4], value =
//   bias[qrow = qt*16 + (lane&15)][key = kt*16 + (lane>>4)*4 + r] * LOG2E
__global__ __launch_bounds__(256) void k_prep(const float* __restrict__ x,
                                              const float* __restrict__ wqkv,
                                              const float* __restrict__ wout,
                                              const float* __restrict__ table,
                                              const int* __restrict__ ridx,
                                              bf16* __restrict__ xb, bf16* __restrict__ wtq,
                                              bf16* __restrict__ wto, bf16* __restrict__ rbb) {
  const int tid = threadIdx.x;
  const int blk = blockIdx.x;
  if (blk < 2048) {
    int t = blk * 256 + tid;
    const float4* s = reinterpret_cast<const float4*>(x) + (size_t)t * 2;
    float4 a = s[0], c = s[1];
    bf16x8 o;
    o[0] = (bf16)a.x; o[1] = (bf16)a.y; o[2] = (bf16)a.z; o[3] = (bf16)a.w;
    o[4] = (bf16)c.x; o[5] = (bf16)c.y; o[6] = (bf16)c.z; o[7] = (bf16)c.w;
    reinterpret_cast<bf16x8*>(xb)[t] = o;
  } else if (blk < 3072) {
    int t = (blk - 2048) * 256 + tid;
    if (t < 196608) {
      int n = t >> 8, k = t & 255;
      wtq[t] = (bf16)wqkv[k * 768 + n];
    } else {
      int t2 = t - 196608;
      int n = t2 >> 8, k = t2 & 255;
      wto[t2] = (bf16)wout[k * 256 + n];
    }
  } else {
    const int bb2 = blk - 3072;  // (qt,kt) tile
    const int qt = bb2 >> 6, kt = bb2 & 63;
    const int r = tid & 3, lane = tid >> 2;
    const int ln = lane & 15, quad = lane >> 4;
    const int qrow = qt * 16 + ln;
    const int key = kt * 16 + quad * 4 + r;
    const int idx = ridx[qrow * 1024 + key];
    const float4* p = reinterpret_cast<const float4*>(table) + idx * 2;
    float4 a = p[0], c = p[1];
    float vals[8] = {a.x, a.y, a.z, a.w, c.x, c.y, c.z, c.w};
    const int base = bb2 * 256 + tid;
#pragma unroll
    for (int h = 0; h < 8; ++h) rbb[h * 1048576 + base] = (bf16)(vals[h] * LOG2E);
  }
}

// ------------------------ 128xBN x(BK=32) bf16 MFMA GEMM, m97-style GL2LDS staging
// EPI 0 (BN=128): q (*scale*log2e) [b,h,n,d]; k [b,h,n,d]; v -> vt[b,h,d,n] via
//   LDS transpose (132-padded tile, coalesced bf16x8 stores).
// EPI 1 (BN=64): out -> fp32 out[m][256] + b_out. BN=64 gives grid (128,4) = 512
//   blocks = 2 blocks/CU (was 1 at BN=128): one block's MFMA hides the other's
//   staging drain. Per-output-element FP order unchanged.
// NOTE: all GL2LDS prefetches are guarded (kt < 224) so none is outstanding at
// kernel exit — dangling LDS-DMA corrupts the successor block's LDS (r9 bug).
template <int EPI>
__global__ __launch_bounds__(256) void k_gemm(const bf16* __restrict__ A,
                                              const bf16* __restrict__ Bt,
                                              bf16* __restrict__ q, bf16* __restrict__ kk,
                                              bf16* __restrict__ vt, float* __restrict__ out,
                                              const float* __restrict__ bout) {
  constexpr int BN = (EPI == 1) ? 64 : 128;  // N-tile width
  constexpr int NJ = BN / 32;                // per-wave 16-col fragments (4 or 2)
  constexpr int SMSZ = (EPI == 0) ? 16896 : 12288;
  // EPI0: staging As[2][4096] | Bs[2][4096], reused post-loop as the 128x132-padded
  // transpose tile (16896 elems). EPI1: As[2][4096] | Bs[2][2048].
  __shared__ __align__(16) bf16 SM[SMSZ];
  bf16(*As)[4096] = reinterpret_cast<bf16(*)[4096]>(SM);
  bf16(*Bs)[BN * 32] = reinterpret_cast<bf16(*)[BN * 32]>(SM + 8192);
  const int tid = threadIdx.x;
  const int ln = tid & 15, quad = (tid >> 4) & 3, wv = tid >> 6;
  const int wm = (wv >> 1) * 64, wn = (wv & 1) * (BN / 2);
  const int m0 = blockIdx.x * 128, n0 = blockIdx.y * BN;
  const int srow = tid >> 2, scg = (tid & 3) * 8;
  const bf16* ag = A + (size_t)(m0 + srow) * 256 + scg;
  const bf16* bg = Bt + (size_t)(n0 + srow) * 256 + scg;
  f32x4 acc[4][NJ] = {};

  GL2LDS16(ag, &As[0][tid * 8]);
  GL2LDS16(ag + 64 * 256, &As[0][2048 + tid * 8]);
  GL2LDS16(bg, &Bs[0][tid * 8]);
  if (EPI == 0) GL2LDS16(bg + 64 * 256, &Bs[0][2048 + tid * 8]);

#pragma unroll 2
  for (int kt = 0; kt < 256; kt += 32) {
    const int cur = (kt >> 5) & 1, nxt = cur ^ 1;
    __syncthreads();
    if (kt < 224) {
      GL2LDS16(ag + kt + 32, &As[nxt][tid * 8]);
      GL2LDS16(ag + 64 * 256 + kt + 32, &As[nxt][2048 + tid * 8]);
      GL2LDS16(bg + kt + 32, &Bs[nxt][tid * 8]);
      if (EPI == 0) GL2LDS16(bg + 64 * 256 + kt + 32, &Bs[nxt][2048 + tid * 8]);
    }
    bf16x8 af[4], bfr[NJ];
#pragma unroll
    for (int i = 0; i < 4; ++i)
      af[i] = *reinterpret_cast<const bf16x8*>(&As[cur][(wm + i * 16 + ln) * 32 + quad * 8]);
#pragma unroll
    for (int j = 0; j < NJ; ++j)
      bfr[j] = *reinterpret_cast<const bf16x8*>(&Bs[cur][(wn + j * 16 + ln) * 32 + quad * 8]);
#pragma unroll
    for (int i = 0; i < 4; ++i)
#pragma unroll
      for (int j = 0; j < NJ; ++j) acc[i][j] = MFMA32(af[i], bfr[j], acc[i][j]);
  }

  if (EPI == 0) {
    const int colbase = n0 + wn;
    const int seg = colbase >> 8;  // block-uniform: y∈{0,1}->q, {2,3}->k, {4,5}->v
    if (seg == 2) {
      // ---- vt epilogue via LDS transpose (coalesced stores) ----
      __syncthreads();  // all waves done with As/Bs reads (no DMA outstanding: kt<224 guard)
#pragma unroll
      for (int i = 0; i < 4; ++i) {
#pragma unroll
        for (int j = 0; j < 4; ++j) {
          bf16x4 t;
#pragma unroll
          for (int r = 0; r < 4; ++r) t[r] = (bf16)acc[i][j][r];
          // T[col][row], padded stride 132: write 4 rows (r) contiguously
          *reinterpret_cast<bf16x4*>(&SM[(wn + j * 16 + ln) * 132 + wm + i * 16 + quad * 4]) = t;
        }
      }
      __syncthreads();
      const int b = m0 >> 10;
      const int nbase = m0 & 1023;  // 128-row tile never crosses a batch boundary
      const int rc = tid & 15, c0 = tid >> 4;
      const int cb0 = n0 & 255;
#pragma unroll
      for (int p = 0; p < 8; ++p) {
        const int c = c0 + p * 16;
        const int gcol = cb0 + c;
        const int h = gcol >> 5, d = gcol & 31;
        bf16* dst = &vt[(b * 8 + h) * 32768 + d * 1024 + nbase + rc * 8];
        *reinterpret_cast<bf16x8*>(dst) =
            *reinterpret_cast<const bf16x8*>(&SM[c * 132 + rc * 8]);
      }
    } else {
      const int cb = colbase & 255;
      const float mul = (seg == 0) ? SCALE * LOG2E : 1.0f;
#pragma unroll
      for (int i = 0; i < 4; ++i) {
        const int gm = m0 + wm + i * 16 + quad * 4;
        const int b = gm >> 10;
#pragma unroll
        for (int j = 0; j < 4; ++j) {
          const int gc = cb + j * 16 + ln;
          const int h = gc >> 5, d = gc & 31;
#pragma unroll
          for (int r = 0; r < 4; ++r) {
            const int nseq = (gm + r) & 1023;
            bf16* dst = (seg == 0) ? q : kk;
            dst[(b * 8 + h) * 32768 + nseq * 32 + d] = (bf16)(acc[i][j][r] * mul);
          }
        }
      }
    }
  } else {
#pragma unroll
    for (int j = 0; j < NJ; ++j) {
      const int gc = n0 + wn + j * 16 + ln;
      const float bb = bout[gc];
#pragma unroll
      for (int i = 0; i < 4; ++i) {
        const int gm = m0 + wm + i * 16 + quad * 4;
#pragma unroll
        for (int r = 0; r < 4; ++r) out[(size_t)(gm + r) * 256 + gc] = acc[i][j][r] + bb;
      }
    }
  }
}

// ----------------------------------------------------------------- flash attention
// R4 state (measured best: 41.9 us). v3 skeleton: 2 q-tiles per wave (32 q-rows),
// grid 1024 blocks = 4 blocks/CU, simple dbuf + __syncthreads.
// REJECTED by measurement (do not retry): ring-3 counted-vmcnt (R3, -3%),
// KVBLK=128 (R5, -1%), ones-MFMA row-sum (R6, -4%: extra MFMA16s sat serially on
// the QK^T->exp->PV critical path; the lsum VALU adds were free in stall slots).
//   - Keeps both-sides XOR swizzles: Ks block swizzle b'=b^((r>>1)&3),
//     Vs [d32][key64] with column swizzle c'=c^(d&7) (sources pre-swizzled,
//     GL2LDS dests linear, reads apply the same XOR).
// All GL2LDS prefetches guarded (it < 15) + trailing barrier: no dangling LDS-DMA.
__global__ __launch_bounds__(256, 4) void k_flash(const bf16* __restrict__ qs,
                                                  const bf16* __restrict__ ks,
                                                  const bf16* __restrict__ vtg,
                                                  const bf16* __restrict__ rbb,
                                                  bf16* __restrict__ ao) {
  __shared__ __align__(16) bf16 Ks[2][2048];  // [buf][row64][d32], block-swizzled
  __shared__ __align__(16) bf16 Vs[2][2048];  // [buf][d32][key64], col-swizzled
  const int tid = threadIdx.x;
  const int lane = tid & 63;
  const int ln = lane & 15, quad = lane >> 4, wv = tid >> 6;
  const int blk = blockIdx.x;
  const int bh = blk & 127;  // %8 == h -> XCD affinity
  const int b = bh >> 3, h = bh & 7;
  const int qtw = (blk >> 7) * 4 + wv;  // 32-row q-pair index [0,32)
  const int q0 = qtw * 32;
  const bf16* qb = qs + bh * 32768;
  const bf16* kb = ks + bh * 32768;
  const bf16* vb = vtg + bh * 32768;
  // bias pointers for the two 16-row q-tiles (qt = 2*qtw, 2*qtw+1)
  const bf16* bbias0 = rbb + h * 1048576 + (2 * qtw) * 16384 + lane * 4;  // + kt16*256
  const bf16* bbias1 = bbias0 + 16384;

  // K staging source: lane covers LDS (r = tid>>2, block b = tid&3); content is
  // global block b ^ ((r>>1)&3). Same 64B/row coverage -> coalescing unchanged.
  const bf16* kg = kb + (tid >> 2) * 32 + (((tid & 3) ^ ((tid >> 3) & 3)) * 8);  // + k0*32
  // V staging source: lane covers LDS (d = tid>>3, col c = tid&7); content is global
  // column c ^ (d&7) of vt row d (contiguous 128B per 8-lane group, permuted within).
  const bf16* vg = vb + (tid >> 3) * 1024 + (((tid & 7) ^ ((tid >> 3) & 7)) * 8);  // + k0

  // Q as B-operand of MFMA32: B[k=d=quad*8+j][n=qrow=ln]
  const bf16x8 qfrag0 = *reinterpret_cast<const bf16x8*>(&qb[(q0 + ln) * 32 + quad * 8]);
  const bf16x8 qfrag1 = *reinterpret_cast<const bf16x8*>(&qb[(q0 + 16 + ln) * 32 + quad * 8]);

  // read-side swizzle indices (loop-invariant)
  const int ksw = (quad ^ ((ln >> 1) & 3)) * 8;  // K 16B-block swizzle
  const int vswl = ln & 7;                       // V column swizzle XOR operand

  f32x4 a00 = {0.f, 0.f, 0.f, 0.f}, a01 = {0.f, 0.f, 0.f, 0.f};
  f32x4 a10 = {0.f, 0.f, 0.f, 0.f}, a11 = {0.f, 0.f, 0.f, 0.f};
  float lsum0 = 0.f, lsum1 = 0.f;

  bf16x4 cbf[2][2][4];  // [buf][qtile][nt]
#pragma unroll
  for (int nt = 0; nt < 4; ++nt) {
    cbf[0][0][nt] = *reinterpret_cast<const bf16x4*>(&bbias0[nt * 256]);
    cbf[0][1][nt] = *reinterpret_cast<const bf16x4*>(&bbias1[nt * 256]);
  }
  GL2LDS16(kg, &Ks[0][tid * 8]);
  GL2LDS16(vg, &Vs[0][tid * 8]);

#pragma unroll 2
  for (int it = 0; it < 16; ++it) {
    const int cur = it & 1, nxt = cur ^ 1;
    const int k0 = it * 64;
    __syncthreads();  // tile `it` staged; prior iteration's LDS reads consumed
    if (it < 15) {    // guarded: NO dangling LDS-DMA at kernel exit
      GL2LDS16(kg + (k0 + 64) * 32, &Ks[nxt][tid * 8]);
      GL2LDS16(vg + k0 + 64, &Vs[nxt][tid * 8]);
#pragma unroll
      for (int nt = 0; nt < 4; ++nt) {
        cbf[nxt][0][nt] = *reinterpret_cast<const bf16x4*>(&bbias0[((it + 1) * 4 + nt) * 256]);
        cbf[nxt][1][nt] = *reinterpret_cast<const bf16x4*>(&bbias1[((it + 1) * 4 + nt) * 256]);
      }
    }
    // K frags: global K[k0+nt*16+ln][quad*8..+7] at swizzled block position
    bf16x8 kf[4];
#pragma unroll
    for (int nt = 0; nt < 4; ++nt)
      kf[nt] = *reinterpret_cast<const bf16x8*>(&Ks[cur][(nt * 16 + ln) * 32 + ksw]);
    // V B-frags for MFMA16: B[k=key=(2nt+q1)*8+q0*4+j][n=d]; Vs[d][key] col-swizzled
    s16x4 vfa[4], vfc[4];
#pragma unroll
    for (int nt = 0; nt < 4; ++nt) {
      const int col = ((2 * nt + (quad >> 1)) ^ vswl) * 8 + (quad & 1) * 4;
      vfa[nt] = *reinterpret_cast<const s16x4*>(&Vs[cur][ln * 64 + col]);
      vfc[nt] = *reinterpret_cast<const s16x4*>(&Vs[cur][(ln + 16) * 64 + col]);
    }
    // S^T = K*Q^T with bias C-init (exp2 domain; scale*log2e folded into q)
    f32x4 s0[4], s1[4];
#pragma unroll
    for (int nt = 0; nt < 4; ++nt) {
      f32x4 c0, c1;
#pragma unroll
      for (int e = 0; e < 4; ++e) {
        c0[e] = (float)cbf[cur][0][nt][e];
        c1[e] = (float)cbf[cur][1][nt][e];
      }
      s0[nt] = MFMA32(kf[nt], qfrag0, c0);
      s1[nt] = MFMA32(kf[nt], qfrag1, c1);
    }
    // P = exp2(S); row sums; pack to MFMA16 A-frags (register identity, r==j)
    s16x4 p0[4], p1[4];
#pragma unroll
    for (int nt = 0; nt < 4; ++nt) {
      bf16x4 t0, t1;
#pragma unroll
      for (int e = 0; e < 4; ++e) {
        s0[nt][e] = __builtin_amdgcn_exp2f(s0[nt][e]);
        t0[e] = (bf16)s0[nt][e];
        s1[nt][e] = __builtin_amdgcn_exp2f(s1[nt][e]);
        t1[e] = (bf16)s1[nt][e];
      }
      lsum0 += (s0[nt][0] + s0[nt][1]) + (s0[nt][2] + s0[nt][3]);
      lsum1 += (s1[nt][0] + s1[nt][1]) + (s1[nt][2] + s1[nt][3]);
      p0[nt] = __builtin_bit_cast(s16x4, t0);
      p1[nt] = __builtin_bit_cast(s16x4, t1);
    }
#pragma unroll
    for (int nt = 0; nt < 4; ++nt) {
      a00 = MFMA16(p0[nt], vfa[nt], a00);
      a01 = MFMA16(p0[nt], vfc[nt], a01);
      a10 = MFMA16(p1[nt], vfa[nt], a10);
      a11 = MFMA16(p1[nt], vfc[nt], a11);
    }
  }
  __syncthreads();  // insurance: drain all waves' outstanding DMA before any exit

  // full row sums: combine the 4 quads' key partials (row = ln per tile)
  lsum0 += __shfl_xor(lsum0, 16, 64);
  lsum0 += __shfl_xor(lsum0, 32, 64);
  lsum1 += __shfl_xor(lsum1, 16, 64);
  lsum1 += __shfl_xor(lsum1, 32, 64);

  // O C-layout: lane holds O[row=quad*4+r][d=ln (a*0) / 16+ln (a*1)]
#pragma unroll
  for (int r = 0; r < 4; ++r) {
    const float inv0 = __builtin_amdgcn_rcpf(__shfl(lsum0, quad * 4 + r, 64));
    const int row0 = q0 + quad * 4 + r;
    bf16* po0 = &ao[(size_t)(b * 1024 + row0) * 256 + h * 32 + ln];
    po0[0] = (bf16)(a00[r] * inv0);
    po0[16] = (bf16)(a01[r] * inv0);
    const float inv1 = __builtin_amdgcn_rcpf(__shfl(lsum1, quad * 4 + r, 64));
    const int row1 = q0 + 16 + quad * 4 + r;
    bf16* po1 = &ao[(size_t)(b * 1024 + row1) * 256 + h * 32 + ln];
    po1[0] = (bf16)(a10[r] * inv1);
    po1[16] = (bf16)(a11[r] * inv1);
  }
}

// ---------------------------------------------------------------------- launcher
extern "C" void kernel_launch(void* const* d_in, const int* in_sizes, int n_in,
                              void* d_out, int out_size, void* d_ws, size_t ws_size,
                              hipStream_t stream) {
  const float* x = (const float*)d_in[0];
  const float* wqkv = (const float*)d_in[1];
  const float* wout = (const float*)d_in[2];
  const float* bout = (const float*)d_in[3];
  const float* btab = (const float*)d_in[4];
  const int* ridx = (const int*)d_in[5];
  float* out = (float*)d_out;

  char* ws = (char*)d_ws;
  bf16* xb  = (bf16*)(ws + 0);           // 8 MB   [16384][256]
  bf16* wtq = (bf16*)(ws + 8388608);     // 384 KB
  bf16* wto = (bf16*)(ws + 8781824);     // 128 KB
  bf16* q   = (bf16*)(ws + 8912896);     // 8 MB   [b,h,n,d] (pre-scaled scale*log2e)
  bf16* k   = (bf16*)(ws + 17301504);    // 8 MB   [b,h,n,d]
  bf16* vt  = (bf16*)(ws + 25690112);    // 8 MB   [b,h,d,n]
  bf16* rb  = (bf16*)(ws + 34078720);    // 16 MB  S^T C-layout bias tiles (*log2e)
  bf16* ao  = (bf16*)(ws + 50855936);    // 8 MB   [16384][256]

  k_prep<<<7168, 256, 0, stream>>>(x, wqkv, wout, btab, ridx, xb, wtq, wto, rb);
  k_gemm<0><<<dim3(128, 6), 256, 0, stream>>>(xb, wtq, q, k, vt, nullptr, nullptr);
  k_flash<<<1024, 256, 0, stream>>>(q, k, vt, rb, ao);
  k_gemm<1><<<dim3(128, 4), 256, 0, stream>>>(ao, wto, nullptr, nullptr, nullptr, out, bout);
}